// Round 10
// baseline (238.594 us; speedup 1.0000x reference)
//
#include <hip/hip_runtime.h>
#include <hip/hip_bf16.h>
#include <stdint.h>

#define M_POS 0.5f
#define M_NEG 0.1f
#define LAM_NEG 1.0f

typedef __attribute__((ext_vector_type(4))) float floatx4;  // 16x16 MFMA accumulator
typedef __attribute__((ext_vector_type(8))) int   intx8;    // 32B fp8 operand (K=128)

union Frag8 { intx8 v; int4 q[2]; };

// ---------------- Kernel A: row sumsq, inv_norm, fp32 -> fp8(e4m3) quantize, zero accs ----
__global__ __launch_bounds__(256) void prep_kernel(
    const float* __restrict__ cb, unsigned char* __restrict__ cb_q,
    float* __restrict__ sq, float* __restrict__ inv_norm,
    unsigned* __restrict__ zero_base, int zero_len,
    int N, int d)
{
    const int gi = blockIdx.x * 256 + threadIdx.x;
    if (gi < zero_len) zero_base[gi] = 0u;

    const int row = blockIdx.x;
    const float* src = cb + (size_t)row * d;
    unsigned char* dst = cb_q + (size_t)row * d;
    const int t = threadIdx.x;

    float s = 0.f;
    for (int c = t * 4; c < d; c += 1024) {
        float4 v = *(const float4*)(src + c);
        s += v.x * v.x + v.y * v.y + v.z * v.z + v.w * v.w;
        int pk = __builtin_amdgcn_cvt_pk_fp8_f32(v.x, v.y, 0, false);   // bytes 0,1
        pk     = __builtin_amdgcn_cvt_pk_fp8_f32(v.z, v.w, pk, true);   // bytes 2,3
        *(int*)(dst + c) = pk;
    }
    for (int o = 32; o > 0; o >>= 1) s += __shfl_down(s, o, 64);
    __shared__ float wsum[4];
    if ((t & 63) == 0) wsum[t >> 6] = s;
    __syncthreads();
    if (t == 0) {
        float tot = wsum[0] + wsum[1] + wsum[2] + wsum[3];
        sq[row] = tot;
        inv_norm[row] = rsqrtf(tot);
    }
}

// ---------------- Kernel B: fused symmetric MX-fp8 Gram GEMM + loss epilogue + finalize ----
// R8 structure (BEST MEASURED: 16x16x128 MX-fp8 unit-scale, single-buffer BK=128,
// 128x128 triangular tiles, wave-uniform pos-skip, tid0-only-fence finalize).
// R10 deltas vs R8: __launch_bounds__(256,4) to raise resident blocks/CU
// (R8 measured 24% occupancy with LDS 33KB admitting 4 blocks), and epilogue
// metadata (j-index norms + pos-overlap ballot) hoisted ABOVE the K-loop so those
// global loads issue 8 K-tiles early. DO NOT double-buffer (R9: 64KB LDS ->
// occupancy 24->17%, gram +21%). DO NOT use 32x32x64 MX (R6: ILP collapse).
// DO NOT per-thread fence (R3: TCC serialization).
__global__ __launch_bounds__(256, 4) void gram_loss_kernel(
    const unsigned char* __restrict__ A,   // N x d fp8
    const float* __restrict__ sq, const float* __restrict__ inv_norm,
    const int* __restrict__ starts, const int* __restrict__ ends,
    const int* __restrict__ max_ip,
    float* __restrict__ pos_acc, float* __restrict__ neg_acc,
    unsigned* __restrict__ counter, float* __restrict__ out,
    int N, int d)
{
    const int M = min(N, max_ip[0] + 1);

    // triangular decode: blockIdx.x -> (by, bx), by <= bx
    const int t = blockIdx.x;
    int bx = (int)((sqrtf(8.f * (float)t + 1.f) - 1.f) * 0.5f);
    while ((bx + 1) * (bx + 2) / 2 <= t) bx++;
    while (bx * (bx + 1) / 2 > t) bx--;
    const int by = t - bx * (bx + 1) / 2;

    const int rowBase = by * 128;
    const int colBase = bx * 128;
    const bool isDiag = (by == bx);

    __shared__ alignas(16) unsigned char ldsA[128 * 128];
    __shared__ alignas(16) unsigned char ldsB[128 * 128];

    const int tid  = threadIdx.x;
    const int wave = tid >> 6;
    const int lane = tid & 63;
    const int wr = (wave >> 1) * 64;
    const int wc = (wave & 1) * 64;

    const int rl = lane & 15;
    const int g  = lane >> 4;       // 0..3 (k-group)
    const int q  = g;
    const int jlo = colBase + wc;
    const int ilo = rowBase + wr;

    // ---- hoisted epilogue metadata: loads issue before the K-loop ----
    int   jn[4];
    float jinv[4];
    bool  jvalid[4];
#pragma unroll
    for (int ct = 0; ct < 4; ++ct) {
        const int j = jlo + ct * 16 + rl;
        jn[ct]  = j;
        jinv[ct] = inv_norm[j];
        jvalid[ct] = (j < M);
    }
    bool posLane = false;
    {
        const int ri = ilo + lane;
        if (ri < M) posLane |= (ends[ri] >= jlo) && (starts[ri] <= jlo + 63);
        if (!isDiag) {
            const int cj = jlo + lane;
            if (cj < M) posLane |= (ends[cj] >= ilo) && (starts[cj] <= ilo + 63);
        }
    }
    const bool fullPath = (__ballot(posLane) != 0ULL);

    floatx4 acc[4][4];
#pragma unroll
    for (int a = 0; a < 4; ++a)
#pragma unroll
        for (int b = 0; b < 4; ++b) acc[a][b] = (floatx4){0.f, 0.f, 0.f, 0.f};

    // staging: per issue, 8 rows x 8 chunks; dst lane-linear; src chunk xor lane-constant.
    const int sRow = lane >> 3;                         // 0..7
    const int sChk = lane & 7;                          // 16B chunk 0..7
    const int srcOffC = ((sChk ^ sRow) * 16);
    const int kTiles = d / 128;                         // 8

    // fragment-read constants: lane holds k = g*32 .. +31 of its row
    const int rx = rl & 7;
    const int c0 = (((2 * g)     ^ rx) * 16);
    const int c1 = (((2 * g + 1) ^ rx) * 16);

    for (int kt = 0; kt < kTiles; ++kt) {
        __syncthreads();
        const int k0 = kt * 128;
#pragma unroll
        for (int h = 0; h < 4; ++h) {
            const int r = wave * 32 + h * 8 + sRow;     // tile row 0..127
            const unsigned char* ga = A + (size_t)(rowBase + r) * d + k0 + srcOffC;
            const unsigned char* gb = A + (size_t)(colBase + r) * d + k0 + srcOffC;
            __builtin_amdgcn_global_load_lds(
                (const __attribute__((address_space(1))) void*)ga,
                (__attribute__((address_space(3))) void*)(ldsA + r * 128 + sChk * 16), 16, 0, 0);
            __builtin_amdgcn_global_load_lds(
                (const __attribute__((address_space(1))) void*)gb,
                (__attribute__((address_space(3))) void*)(ldsB + r * 128 + sChk * 16), 16, 0, 0);
        }
        __syncthreads();

        Frag8 af[4], bf[4];
#pragma unroll
        for (int t4 = 0; t4 < 4; ++t4) {
            const unsigned char* pa = ldsA + (wr + t4 * 16 + rl) * 128;
            af[t4].q[0] = *(const int4*)(pa + c0);
            af[t4].q[1] = *(const int4*)(pa + c1);
            const unsigned char* pb = ldsB + (wc + t4 * 16 + rl) * 128;
            bf[t4].q[0] = *(const int4*)(pb + c0);
            bf[t4].q[1] = *(const int4*)(pb + c1);
        }
#pragma unroll
        for (int rt = 0; rt < 4; ++rt)
#pragma unroll
            for (int ct = 0; ct < 4; ++ct)
                acc[rt][ct] = __builtin_amdgcn_mfma_scale_f32_16x16x128_f8f6f4(
                    af[rt].v, bf[ct].v, acc[rt][ct], 0, 0, 0, 127, 0, 127);
    }

    // ---- epilogue (16x16 C/D: col=lane&15, row=(lane>>4)*4+reg) ----
    float posc[4] = {0.f, 0.f, 0.f, 0.f};
    float negc[4] = {0.f, 0.f, 0.f, 0.f};

    if (fullPath) {
        int   jns[4], jne[4];
        float jsq[4];
#pragma unroll
        for (int ct = 0; ct < 4; ++ct) {
            jsq[ct] = sq[jn[ct]];
            jns[ct] = jvalid[ct] ? starts[jn[ct]] : 0;
            jne[ct] = jvalid[ct] ? ends[jn[ct]]   : -1;
        }
#pragma unroll
        for (int rt = 0; rt < 4; ++rt) {
            const int ibase = ilo + rt * 16 + q * 4;
#pragma unroll
            for (int reg = 0; reg < 4; ++reg) {
                const int i = ibase + reg;
                const bool rowValid = (i < M);
                const int ns = rowValid ? starts[i] : 0;
                const int ne = rowValid ? ends[i]   : -1;
                const float iinv = inv_norm[i];
                const float isq  = sq[i];
                float posp = 0.f, negp = 0.f;
#pragma unroll
                for (int ct = 0; ct < 4; ++ct) {
                    const float dot = acc[rt][ct][reg];
                    const int j = jn[ct];
                    float cosv = dot * iinv * jinv[ct];
                    cosv = fminf(fmaxf(cosv, -1.f), 1.f);
                    float tn = fmaxf(fabsf(cosv) - M_NEG, 0.f);
                    const float nterm = tn * tn;
                    const float d2 = fmaxf(isq + jsq[ct] - 2.f * dot, 0.f);
                    float tp = fmaxf(sqrtf(d2) - M_POS, 0.f);
                    const float pterm = tp * tp;
                    const bool dg = (j == i);
                    if (rowValid) {
                        const bool in_r = (j >= ns) && (j <= ne);
                        if (in_r && !dg) posp += pterm;
                        if (!in_r || dg) negp += nterm;
                    }
                    if (!isDiag && jvalid[ct]) {
                        const bool in_c = (i >= jns[ct]) && (i <= jne[ct]);
                        if (in_c && !dg) posc[ct] += pterm;
                        if (!in_c || dg) negc[ct] += nterm;
                    }
                }
#pragma unroll
                for (int m = 1; m < 16; m <<= 1) {
                    posp += __shfl_xor(posp, m, 64);
                    negp += __shfl_xor(negp, m, 64);
                }
                if (rowValid && rl == 0) {
                    atomicAdd(&pos_acc[i], posp);
                    atomicAdd(&neg_acc[i], negp);
                }
            }
        }
        if (!isDiag) {
#pragma unroll
            for (int ct = 0; ct < 4; ++ct) {
                posc[ct] += __shfl_xor(posc[ct], 16, 64);
                posc[ct] += __shfl_xor(posc[ct], 32, 64);
                negc[ct] += __shfl_xor(negc[ct], 16, 64);
                negc[ct] += __shfl_xor(negc[ct], 32, 64);
            }
            if (q == 0) {
#pragma unroll
                for (int ct = 0; ct < 4; ++ct) {
                    if (jvalid[ct]) {
                        atomicAdd(&pos_acc[jn[ct]], posc[ct]);
                        atomicAdd(&neg_acc[jn[ct]], negc[ct]);
                    }
                }
            }
        }
    } else {
        // fast path: every element is a negative for both its row and its column
#pragma unroll
        for (int rt = 0; rt < 4; ++rt) {
            const int ibase = ilo + rt * 16 + q * 4;
#pragma unroll
            for (int reg = 0; reg < 4; ++reg) {
                const int i = ibase + reg;
                const float iinv = inv_norm[i];
                float negp = 0.f;
#pragma unroll
                for (int ct = 0; ct < 4; ++ct) {
                    const float dot = acc[rt][ct][reg];
                    float cosv = dot * iinv * jinv[ct];
                    cosv = fminf(fmaxf(cosv, -1.f), 1.f);
                    float tn = fmaxf(fabsf(cosv) - M_NEG, 0.f);
                    const float nterm = tn * tn;
                    negp += nterm;
                    negc[ct] += nterm;
                }
#pragma unroll
                for (int m = 1; m < 16; m <<= 1)
                    negp += __shfl_xor(negp, m, 64);
                if ((i < M) && rl == 0)
                    atomicAdd(&neg_acc[i], negp);
            }
        }
        if (!isDiag) {
#pragma unroll
            for (int ct = 0; ct < 4; ++ct) {
                negc[ct] += __shfl_xor(negc[ct], 16, 64);
                negc[ct] += __shfl_xor(negc[ct], 32, 64);
            }
            if (q == 0) {
#pragma unroll
                for (int ct = 0; ct < 4; ++ct)
                    if (jvalid[ct])
                        atomicAdd(&neg_acc[jn[ct]], negc[ct]);
            }
        }
    }

    // ---- last-block finalize (fence/atomic by tid0 only — validated R7) ----
    __shared__ bool amLast;
    __syncthreads();
    if (tid == 0) {
        __threadfence();
        unsigned old = atomicAdd(counter, 1u);
        amLast = (old == (unsigned)(gridDim.x - 1));
    }
    __syncthreads();
    if (amLast) {
        __threadfence();
        float total = 0.f;
        int cnt = 0;
        for (int i = tid; i < M; i += 256) {
            const float pa = __hip_atomic_load(&pos_acc[i], __ATOMIC_RELAXED, __HIP_MEMORY_SCOPE_AGENT);
            const float na = __hip_atomic_load(&neg_acc[i], __ATOMIC_RELAXED, __HIP_MEMORY_SCOPE_AGENT);
            const int ns = starts[i], ne = ends[i];
            const int lo = max(ns, 0), hi = min(ne, N - 1);
            const int inr = max(hi - lo + 1, 0);
            const bool dg = (i >= ns) && (i <= ne);
            const int pos_cnt = inr - (dg ? 1 : 0);
            const int neg_cnt = N - inr + (dg ? 1 : 0);
            if (pos_cnt > 0 && neg_cnt > 0) {
                total += pa / (float)max(pos_cnt, 1)
                       + LAM_NEG * na / (float)max(neg_cnt, 1);
                cnt++;
            }
        }
        for (int o = 32; o > 0; o >>= 1) {
            total += __shfl_down(total, o, 64);
            cnt   += __shfl_down(cnt, o, 64);
        }
        __shared__ float fin_ts[4];
        __shared__ int   fin_cs[4];
        if ((tid & 63) == 0) { fin_ts[tid >> 6] = total; fin_cs[tid >> 6] = cnt; }
        __syncthreads();
        if (tid == 0) {
            float T = fin_ts[0] + fin_ts[1] + fin_ts[2] + fin_ts[3];
            int   C = fin_cs[0] + fin_cs[1] + fin_cs[2] + fin_cs[3];
            out[0] = (C > 0) ? T / (float)C : 0.f;
        }
    }
}

extern "C" void kernel_launch(void* const* d_in, const int* in_sizes, int n_in,
                              void* d_out, int out_size, void* d_ws, size_t ws_size,
                              hipStream_t stream) {
    const float* cb     = (const float*)d_in[0];
    const int*   starts = (const int*)d_in[1];
    const int*   ends   = (const int*)d_in[2];
    const int*   max_ip = (const int*)d_in[3];
    float* out = (float*)d_out;

    const int N = in_sizes[1];
    const int d = in_sizes[0] / N;

    char* ws = (char*)d_ws;
    unsigned char* cb_q = (unsigned char*)ws;
    size_t off = ((size_t)N * d + 255) & ~(size_t)255;
    float* sq       = (float*)(ws + off); off += (size_t)N * 4;
    float* inv_norm = (float*)(ws + off); off += (size_t)N * 4;
    float* pos_acc  = (float*)(ws + off); off += (size_t)N * 4;
    float* neg_acc  = (float*)(ws + off); off += (size_t)N * 4;
    unsigned* counter = (unsigned*)(ws + off); off += 256;

    // prep zeroes pos_acc/neg_acc/counter (2N+1 u32, contiguous)
    prep_kernel<<<N, 256, 0, stream>>>(cb, cb_q, sq, inv_norm,
                                       (unsigned*)pos_acc, 2 * N + 1, N, d);

    const int nb = N / 128;
    const int nBlocks = nb * (nb + 1) / 2;   // upper-triangular tiles
    gram_loss_kernel<<<nBlocks, 256, 0, stream>>>(cb_q, sq, inv_norm, starts, ends,
                                                  max_ip, pos_acc, neg_acc, counter,
                                                  out, N, d);
}

// Round 11
// 221.930 us; speedup vs baseline: 1.0751x; 1.0751x over previous
//
#include <hip/hip_runtime.h>
#include <hip/hip_bf16.h>
#include <stdint.h>

#define M_POS 0.5f
#define M_NEG 0.1f
#define LAM_NEG 1.0f

typedef __attribute__((ext_vector_type(4))) float floatx4;  // 16x16 MFMA accumulator
using f8x8 = long;   // 8 fp8 bytes = 2 VGPRs (fp8 16x16x32 MFMA operand)

// ---------------- Kernel A: row sumsq, inv_norm, fp32 -> fp8(e4m3) quantize, zero accs ----
__global__ __launch_bounds__(256) void prep_kernel(
    const float* __restrict__ cb, unsigned char* __restrict__ cb_q,
    float* __restrict__ sq, float* __restrict__ inv_norm,
    unsigned* __restrict__ zero_base, int zero_len,
    int N, int d)
{
    const int gi = blockIdx.x * 256 + threadIdx.x;
    if (gi < zero_len) zero_base[gi] = 0u;

    const int row = blockIdx.x;
    const float* src = cb + (size_t)row * d;
    unsigned char* dst = cb_q + (size_t)row * d;
    const int t = threadIdx.x;

    float s = 0.f;
    for (int c = t * 4; c < d; c += 1024) {
        float4 v = *(const float4*)(src + c);
        s += v.x * v.x + v.y * v.y + v.z * v.z + v.w * v.w;
        int pk = __builtin_amdgcn_cvt_pk_fp8_f32(v.x, v.y, 0, false);   // bytes 0,1
        pk     = __builtin_amdgcn_cvt_pk_fp8_f32(v.z, v.w, pk, true);   // bytes 2,3
        *(int*)(dst + c) = pk;
    }
    for (int o = 32; o > 0; o >>= 1) s += __shfl_down(s, o, 64);
    __shared__ float wsum[4];
    if ((t & 63) == 0) wsum[t >> 6] = s;
    __syncthreads();
    if (t == 0) {
        float tot = wsum[0] + wsum[1] + wsum[2] + wsum[3];
        sq[row] = tot;
        inv_norm[row] = rsqrtf(tot);
    }
}

// ---------------- Kernel B: fused symmetric fp8 Gram GEMM + loss epilogue + finalize ------
// R11: R5's verified 16x16x32 fp8 layout (BK=64, b64 frag reads, xor swizzle) with
// DOUBLE-BUFFERED LDS at 32 KB TOTAL (2 bufs x 2 matrices x 8 KB) — R9's dbuf idea
// with its occupancy confounder removed (R9's 64 KB LDS dropped occupancy 24->17%).
// One barrier per kt; prefetch kt+1 issues right after the barrier and completes
// during kt's ds_read+MFMA phase, so the barrier's vmcnt drain is cheap.
// launch_bounds(256,3): R10 proved (256,4) forces a 64-VGPR cap -> scratch spills
// (WRITE_SIZE 70 MB). No metadata hoisting (live-reg cost, no measured benefit).
// Last-block finalize with tid0-only fence (validated R7; R3's per-thread fences bad).
__global__ __launch_bounds__(256, 3) void gram_loss_kernel(
    const unsigned char* __restrict__ A,   // N x d fp8
    const float* __restrict__ sq, const float* __restrict__ inv_norm,
    const int* __restrict__ starts, const int* __restrict__ ends,
    const int* __restrict__ max_ip,
    float* __restrict__ pos_acc, float* __restrict__ neg_acc,
    unsigned* __restrict__ counter, float* __restrict__ out,
    int N, int d)
{
    const int M = min(N, max_ip[0] + 1);

    // triangular decode: blockIdx.x -> (by, bx), by <= bx
    const int t = blockIdx.x;
    int bx = (int)((sqrtf(8.f * (float)t + 1.f) - 1.f) * 0.5f);
    while ((bx + 1) * (bx + 2) / 2 <= t) bx++;
    while (bx * (bx + 1) / 2 > t) bx--;
    const int by = t - bx * (bx + 1) / 2;

    const int rowBase = by * 128;
    const int colBase = bx * 128;
    const bool isDiag = (by == bx);

    // [buf][A/B][128 rows x 64 B] = 32 KB total (same footprint as R8)
    __shared__ alignas(16) unsigned char lds[2][2][128 * 64];

    const int tid  = threadIdx.x;
    const int wave = tid >> 6;
    const int lane = tid & 63;
    const int wr = (wave >> 1) * 64;
    const int wc = (wave & 1) * 64;

    floatx4 acc[4][4];
#pragma unroll
    for (int a = 0; a < 4; ++a)
#pragma unroll
        for (int b = 0; b < 4; ++b) acc[a][b] = (floatx4){0.f, 0.f, 0.f, 0.f};

    // staging (R5 layout): per issue 16 rows x 4 chunks; dst lane-linear;
    // physical chunk q of row r holds logical chunk q^((r>>1)&3).
    const int sR = lane >> 2;                       // local row 0..15
    const int sQ = lane & 3;                        // 16B chunk 0..3
    const int kTiles = d / 64;                      // 16

    // fragment-read constants (R5, verified absmax 0)
    const int rl = lane & 15;
    const int g  = lane >> 4;       // 0..3
    const int rowx = (rl >> 1) & 3;
    const int ghalf = g >> 1;
    const int godd  = (g & 1) * 8;

    auto stage = [&](int kt, int buf) {
        const int k0 = kt * 64;
#pragma unroll
        for (int h = 0; h < 2; ++h) {
            const int r = wave * 32 + h * 16 + sR;          // tile row 0..127
            const int srcQ = sQ ^ ((r >> 1) & 3);
            const unsigned char* ga = A + (size_t)(rowBase + r) * d + k0 + srcQ * 16;
            const unsigned char* gb = A + (size_t)(colBase + r) * d + k0 + srcQ * 16;
            __builtin_amdgcn_global_load_lds(
                (const __attribute__((address_space(1))) void*)ga,
                (__attribute__((address_space(3))) void*)(&lds[buf][0][0] + r * 64 + sQ * 16), 16, 0, 0);
            __builtin_amdgcn_global_load_lds(
                (const __attribute__((address_space(1))) void*)gb,
                (__attribute__((address_space(3))) void*)(&lds[buf][1][0] + r * 64 + sQ * 16), 16, 0, 0);
        }
    };

    stage(0, 0);   // prologue prefetch

    for (int kt = 0; kt < kTiles; ++kt) {
        const int cur = kt & 1;
        __syncthreads();   // buf[cur] writes (issued one iter ago) visible; prev reads done
        if (kt + 1 < kTiles) stage(kt + 1, cur ^ 1);

        const unsigned char* ldsA = &lds[cur][0][0];
        const unsigned char* ldsB = &lds[cur][1][0];
#pragma unroll
        for (int ko = 0; ko < 2; ++ko) {
            const int phys16 = ((ko * 2 + ghalf) ^ rowx);
            const int koff = phys16 * 16 + godd;
            f8x8 af[4], bf[4];
#pragma unroll
            for (int t4 = 0; t4 < 4; ++t4) {
                const int ra = wr + t4 * 16 + rl;
                const int rb = wc + t4 * 16 + rl;
                af[t4] = *(const f8x8*)(ldsA + ra * 64 + koff);
                bf[t4] = *(const f8x8*)(ldsB + rb * 64 + koff);
            }
#pragma unroll
            for (int rt = 0; rt < 4; ++rt)
#pragma unroll
                for (int ct = 0; ct < 4; ++ct)
                    acc[rt][ct] = __builtin_amdgcn_mfma_f32_16x16x32_fp8_fp8(
                        af[rt], bf[ct], acc[rt][ct], 0, 0, 0);
        }
    }

    // ---- epilogue (16x16 C/D: col=lane&15, row=(lane>>4)*4+reg) ----
    const int q  = lane >> 4;
    const int jlo = colBase + wc;
    const int ilo = rowBase + wr;

    int   jn[4];
    float jinv[4];
    bool  jvalid[4];
#pragma unroll
    for (int ct = 0; ct < 4; ++ct) {
        const int j = jlo + ct * 16 + rl;
        jn[ct]  = j;
        jinv[ct] = inv_norm[j];
        jvalid[ct] = (j < M);
    }

    // wave-uniform positive-pair possibility check
    bool posLane = false;
    {
        const int ri = ilo + lane;
        if (ri < M) posLane |= (ends[ri] >= jlo) && (starts[ri] <= jlo + 63);
        if (!isDiag) {
            const int cj = jlo + lane;
            if (cj < M) posLane |= (ends[cj] >= ilo) && (starts[cj] <= ilo + 63);
        }
    }
    const bool fullPath = (__ballot(posLane) != 0ULL);

    float posc[4] = {0.f, 0.f, 0.f, 0.f};
    float negc[4] = {0.f, 0.f, 0.f, 0.f};

    if (fullPath) {
        int   jns[4], jne[4];
        float jsq[4];
#pragma unroll
        for (int ct = 0; ct < 4; ++ct) {
            jsq[ct] = sq[jn[ct]];
            jns[ct] = jvalid[ct] ? starts[jn[ct]] : 0;
            jne[ct] = jvalid[ct] ? ends[jn[ct]]   : -1;
        }
#pragma unroll
        for (int rt = 0; rt < 4; ++rt) {
            const int ibase = ilo + rt * 16 + q * 4;
#pragma unroll
            for (int reg = 0; reg < 4; ++reg) {
                const int i = ibase + reg;
                const bool rowValid = (i < M);
                const int ns = rowValid ? starts[i] : 0;
                const int ne = rowValid ? ends[i]   : -1;
                const float iinv = inv_norm[i];
                const float isq  = sq[i];
                float posp = 0.f, negp = 0.f;
#pragma unroll
                for (int ct = 0; ct < 4; ++ct) {
                    const float dot = acc[rt][ct][reg];
                    const int j = jn[ct];
                    float cosv = dot * iinv * jinv[ct];
                    cosv = fminf(fmaxf(cosv, -1.f), 1.f);
                    float tn = fmaxf(fabsf(cosv) - M_NEG, 0.f);
                    const float nterm = tn * tn;
                    const float d2 = fmaxf(isq + jsq[ct] - 2.f * dot, 0.f);
                    float tp = fmaxf(sqrtf(d2) - M_POS, 0.f);
                    const float pterm = tp * tp;
                    const bool dg = (j == i);
                    if (rowValid) {
                        const bool in_r = (j >= ns) && (j <= ne);
                        if (in_r && !dg) posp += pterm;
                        if (!in_r || dg) negp += nterm;
                    }
                    if (!isDiag && jvalid[ct]) {
                        const bool in_c = (i >= jns[ct]) && (i <= jne[ct]);
                        if (in_c && !dg) posc[ct] += pterm;
                        if (!in_c || dg) negc[ct] += nterm;
                    }
                }
#pragma unroll
                for (int m = 1; m < 16; m <<= 1) {
                    posp += __shfl_xor(posp, m, 64);
                    negp += __shfl_xor(negp, m, 64);
                }
                if (rowValid && rl == 0) {
                    atomicAdd(&pos_acc[i], posp);
                    atomicAdd(&neg_acc[i], negp);
                }
            }
        }
        if (!isDiag) {
#pragma unroll
            for (int ct = 0; ct < 4; ++ct) {
                posc[ct] += __shfl_xor(posc[ct], 16, 64);
                posc[ct] += __shfl_xor(posc[ct], 32, 64);
                negc[ct] += __shfl_xor(negc[ct], 16, 64);
                negc[ct] += __shfl_xor(negc[ct], 32, 64);
            }
            if (q == 0) {
#pragma unroll
                for (int ct = 0; ct < 4; ++ct) {
                    if (jvalid[ct]) {
                        atomicAdd(&pos_acc[jn[ct]], posc[ct]);
                        atomicAdd(&neg_acc[jn[ct]], negc[ct]);
                    }
                }
            }
        }
    } else {
        // fast path: every element is a negative for both its row and its column
#pragma unroll
        for (int rt = 0; rt < 4; ++rt) {
            const int ibase = ilo + rt * 16 + q * 4;
#pragma unroll
            for (int reg = 0; reg < 4; ++reg) {
                const int i = ibase + reg;
                const float iinv = inv_norm[i];
                float negp = 0.f;
#pragma unroll
                for (int ct = 0; ct < 4; ++ct) {
                    const float dot = acc[rt][ct][reg];
                    float cosv = dot * iinv * jinv[ct];
                    cosv = fminf(fmaxf(cosv, -1.f), 1.f);
                    float tn = fmaxf(fabsf(cosv) - M_NEG, 0.f);
                    const float nterm = tn * tn;
                    negp += nterm;
                    negc[ct] += nterm;
                }
#pragma unroll
                for (int m = 1; m < 16; m <<= 1)
                    negp += __shfl_xor(negp, m, 64);
                if ((i < M) && rl == 0)
                    atomicAdd(&neg_acc[i], negp);
            }
        }
        if (!isDiag) {
#pragma unroll
            for (int ct = 0; ct < 4; ++ct) {
                negc[ct] += __shfl_xor(negc[ct], 16, 64);
                negc[ct] += __shfl_xor(negc[ct], 32, 64);
            }
            if (q == 0) {
#pragma unroll
                for (int ct = 0; ct < 4; ++ct)
                    if (jvalid[ct])
                        atomicAdd(&neg_acc[jn[ct]], negc[ct]);
            }
        }
    }

    // ---- last-block finalize (fence/atomic by tid0 only — validated R7) ----
    __shared__ bool amLast;
    __syncthreads();
    if (tid == 0) {
        __threadfence();
        unsigned old = atomicAdd(counter, 1u);
        amLast = (old == (unsigned)(gridDim.x - 1));
    }
    __syncthreads();
    if (amLast) {
        __threadfence();
        float total = 0.f;
        int cnt = 0;
        for (int i = tid; i < M; i += 256) {
            const float pa = __hip_atomic_load(&pos_acc[i], __ATOMIC_RELAXED, __HIP_MEMORY_SCOPE_AGENT);
            const float na = __hip_atomic_load(&neg_acc[i], __ATOMIC_RELAXED, __HIP_MEMORY_SCOPE_AGENT);
            const int ns = starts[i], ne = ends[i];
            const int lo = max(ns, 0), hi = min(ne, N - 1);
            const int inr = max(hi - lo + 1, 0);
            const bool dg = (i >= ns) && (i <= ne);
            const int pos_cnt = inr - (dg ? 1 : 0);
            const int neg_cnt = N - inr + (dg ? 1 : 0);
            if (pos_cnt > 0 && neg_cnt > 0) {
                total += pa / (float)max(pos_cnt, 1)
                       + LAM_NEG * na / (float)max(neg_cnt, 1);
                cnt++;
            }
        }
        for (int o = 32; o > 0; o >>= 1) {
            total += __shfl_down(total, o, 64);
            cnt   += __shfl_down(cnt, o, 64);
        }
        __shared__ float fin_ts[4];
        __shared__ int   fin_cs[4];
        if ((tid & 63) == 0) { fin_ts[tid >> 6] = total; fin_cs[tid >> 6] = cnt; }
        __syncthreads();
        if (tid == 0) {
            float T = fin_ts[0] + fin_ts[1] + fin_ts[2] + fin_ts[3];
            int   C = fin_cs[0] + fin_cs[1] + fin_cs[2] + fin_cs[3];
            out[0] = (C > 0) ? T / (float)C : 0.f;
        }
    }
}

extern "C" void kernel_launch(void* const* d_in, const int* in_sizes, int n_in,
                              void* d_out, int out_size, void* d_ws, size_t ws_size,
                              hipStream_t stream) {
    const float* cb     = (const float*)d_in[0];
    const int*   starts = (const int*)d_in[1];
    const int*   ends   = (const int*)d_in[2];
    const int*   max_ip = (const int*)d_in[3];
    float* out = (float*)d_out;

    const int N = in_sizes[1];
    const int d = in_sizes[0] / N;

    char* ws = (char*)d_ws;
    unsigned char* cb_q = (unsigned char*)ws;
    size_t off = ((size_t)N * d + 255) & ~(size_t)255;
    float* sq       = (float*)(ws + off); off += (size_t)N * 4;
    float* inv_norm = (float*)(ws + off); off += (size_t)N * 4;
    float* pos_acc  = (float*)(ws + off); off += (size_t)N * 4;
    float* neg_acc  = (float*)(ws + off); off += (size_t)N * 4;
    unsigned* counter = (unsigned*)(ws + off); off += 256;

    // prep zeroes pos_acc/neg_acc/counter (2N+1 u32, contiguous)
    prep_kernel<<<N, 256, 0, stream>>>(cb, cb_q, sq, inv_norm,
                                       (unsigned*)pos_acc, 2 * N + 1, N, d);

    const int nb = N / 128;
    const int nBlocks = nb * (nb + 1) / 2;   // upper-triangular tiles
    gram_loss_kernel<<<nBlocks, 256, 0, stream>>>(cb_q, sq, inv_norm, starts, ends,
                                                  max_ip, pos_acc, neg_acc, counter,
                                                  out, N, d);
}

// Round 12
// 206.100 us; speedup vs baseline: 1.1577x; 1.0768x over previous
//
#include <hip/hip_runtime.h>
#include <hip/hip_bf16.h>
#include <stdint.h>

#define M_POS 0.5f
#define M_NEG 0.1f
#define LAM_NEG 1.0f

typedef __attribute__((ext_vector_type(4))) float floatx4;  // MFMA accumulator
using f8x8 = long;   // 8 fp8 bytes = 2 VGPRs (fp8 16x16x32 MFMA operand)

// ---------------- Kernel A: row sumsq, inv_norm, fp32 -> fp8(e4m3) quantize, zero accs ----
__global__ __launch_bounds__(256) void prep_kernel(
    const float* __restrict__ cb, unsigned char* __restrict__ cb_q,
    float* __restrict__ sq, float* __restrict__ inv_norm,
    unsigned* __restrict__ zero_base, int zero_len,
    int N, int d)
{
    const int gi = blockIdx.x * 256 + threadIdx.x;
    if (gi < zero_len) zero_base[gi] = 0u;

    const int row = blockIdx.x;
    const float* src = cb + (size_t)row * d;
    unsigned char* dst = cb_q + (size_t)row * d;
    const int t = threadIdx.x;

    float s = 0.f;
    for (int c = t * 4; c < d; c += 1024) {
        float4 v = *(const float4*)(src + c);
        s += v.x * v.x + v.y * v.y + v.z * v.z + v.w * v.w;
        int pk = __builtin_amdgcn_cvt_pk_fp8_f32(v.x, v.y, 0, false);   // bytes 0,1
        pk     = __builtin_amdgcn_cvt_pk_fp8_f32(v.z, v.w, pk, true);   // bytes 2,3
        *(int*)(dst + c) = pk;
    }
    for (int o = 32; o > 0; o >>= 1) s += __shfl_down(s, o, 64);
    __shared__ float wsum[4];
    if ((t & 63) == 0) wsum[t >> 6] = s;
    __syncthreads();
    if (t == 0) {
        float tot = wsum[0] + wsum[1] + wsum[2] + wsum[3];
        sq[row] = tot;
        inv_norm[row] = rsqrtf(tot);
    }
}

// ---------------- Kernel B: fused symmetric fp8 Gram GEMM + loss epilogue + finalize ------
// R12 = R7's kernel (non-MX fp8 16x16x32, BK=128, single-buffer, b64 frag reads with
// xor swizzle) + __launch_bounds__(256,4). Register ledger (trace VGPR_Count is ARCH-only;
// 64-AGPR acc is extra): R7 used 68 arch + 64 acc = 132/wave -> 3 waves/SIMD -> 3
// independent blocks/CU. Forcing 4 waves/EU caps total at 128 -> needs arch<=64, only 4
// below R7's natural 68 -> expect ~zero spills (UNLIKE R10: MX operands cost 64 VGPRs,
// cap 128 vs need ~140 -> 70MB spill traffic; non-MX operands cost 16).
// Goal: 4 independent barrier groups + 16 waves/CU to hide staging service time.
// Canaries: VGPR_Count==64, WRITE_SIZE ~10KB. Last-block finalize tid0-only fence (R7).
__global__ __launch_bounds__(256, 4) void gram_loss_kernel(
    const unsigned char* __restrict__ A,   // N x d fp8
    const float* __restrict__ sq, const float* __restrict__ inv_norm,
    const int* __restrict__ starts, const int* __restrict__ ends,
    const int* __restrict__ max_ip,
    float* __restrict__ pos_acc, float* __restrict__ neg_acc,
    unsigned* __restrict__ counter, float* __restrict__ out,
    int N, int d)
{
    const int M = min(N, max_ip[0] + 1);

    // triangular decode: blockIdx.x -> (by, bx), by <= bx
    const int t = blockIdx.x;
    int bx = (int)((sqrtf(8.f * (float)t + 1.f) - 1.f) * 0.5f);
    while ((bx + 1) * (bx + 2) / 2 <= t) bx++;
    while (bx * (bx + 1) / 2 > t) bx--;
    const int by = t - bx * (bx + 1) / 2;

    const int rowBase = by * 128;
    const int colBase = bx * 128;
    const bool isDiag = (by == bx);

    __shared__ alignas(16) unsigned char ldsA[128 * 128];
    __shared__ alignas(16) unsigned char ldsB[128 * 128];

    const int tid  = threadIdx.x;
    const int wave = tid >> 6;
    const int lane = tid & 63;
    const int wr = (wave >> 1) * 64;
    const int wc = (wave & 1) * 64;

    floatx4 acc[4][4];
#pragma unroll
    for (int a = 0; a < 4; ++a)
#pragma unroll
        for (int b = 0; b < 4; ++b) acc[a][b] = (floatx4){0.f, 0.f, 0.f, 0.f};

    // staging: per issue, 8 rows x 8 chunks (1 KB contiguous LDS); dst lane-linear.
    // srcQ xor is lane-constant: r&7 == lane>>3 for all h/kt.
    const int sRow = lane >> 3;                         // 0..7
    const int sChk = lane & 7;                          // 16B chunk 0..7
    const int srcOffC = ((sChk ^ sRow) * 16);           // logical chunk fetched
    const int kTiles = d / 128;                         // 8

    // fragment-read constants
    const int rl = lane & 15;
    const int g  = lane >> 4;       // 0..3
    const int fragOddB = (g & 1) * 8;
    const int fragChkBase = g >> 1;                     // logical chunk = 2*ko + (g>>1)
    const int rx = rl & 7;

    for (int kt = 0; kt < kTiles; ++kt) {
        __syncthreads();
        const int k0 = kt * 128;
#pragma unroll
        for (int h = 0; h < 4; ++h) {
            const int r = wave * 32 + h * 8 + sRow;     // tile row 0..127
            const unsigned char* ga = A + (size_t)(rowBase + r) * d + k0 + srcOffC;
            const unsigned char* gb = A + (size_t)(colBase + r) * d + k0 + srcOffC;
            __builtin_amdgcn_global_load_lds(
                (const __attribute__((address_space(1))) void*)ga,
                (__attribute__((address_space(3))) void*)(ldsA + r * 128 + sChk * 16), 16, 0, 0);
            __builtin_amdgcn_global_load_lds(
                (const __attribute__((address_space(1))) void*)gb,
                (__attribute__((address_space(3))) void*)(ldsB + r * 128 + sChk * 16), 16, 0, 0);
        }
        __syncthreads();

#pragma unroll
        for (int ko = 0; ko < 4; ++ko) {
            const int koff = ((2 * ko + fragChkBase) ^ rx) * 16 + fragOddB;
            f8x8 af[4], bf[4];
#pragma unroll
            for (int t4 = 0; t4 < 4; ++t4) {
                const int ra = wr + t4 * 16 + rl;
                const int rb = wc + t4 * 16 + rl;
                af[t4] = *(const f8x8*)(ldsA + ra * 128 + koff);
                bf[t4] = *(const f8x8*)(ldsB + rb * 128 + koff);
            }
#pragma unroll
            for (int rt = 0; rt < 4; ++rt)
#pragma unroll
                for (int ct = 0; ct < 4; ++ct)
                    acc[rt][ct] = __builtin_amdgcn_mfma_f32_16x16x32_fp8_fp8(
                        af[rt], bf[ct], acc[rt][ct], 0, 0, 0);
        }
    }

    // ---- epilogue (16x16 C/D: col=lane&15, row=(lane>>4)*4+reg) ----
    const int q  = lane >> 4;
    const int jlo = colBase + wc;
    const int ilo = rowBase + wr;

    int   jn[4];
    float jinv[4];
    bool  jvalid[4];
#pragma unroll
    for (int ct = 0; ct < 4; ++ct) {
        const int j = jlo + ct * 16 + rl;
        jn[ct]  = j;
        jinv[ct] = inv_norm[j];
        jvalid[ct] = (j < M);
    }

    // wave-uniform positive-pair possibility check
    bool posLane = false;
    {
        const int ri = ilo + lane;
        if (ri < M) posLane |= (ends[ri] >= jlo) && (starts[ri] <= jlo + 63);
        if (!isDiag) {
            const int cj = jlo + lane;
            if (cj < M) posLane |= (ends[cj] >= ilo) && (starts[cj] <= ilo + 63);
        }
    }
    const bool fullPath = (__ballot(posLane) != 0ULL);

    float posc[4] = {0.f, 0.f, 0.f, 0.f};
    float negc[4] = {0.f, 0.f, 0.f, 0.f};

    if (fullPath) {
        int   jns[4], jne[4];
        float jsq[4];
#pragma unroll
        for (int ct = 0; ct < 4; ++ct) {
            jsq[ct] = sq[jn[ct]];
            jns[ct] = jvalid[ct] ? starts[jn[ct]] : 0;
            jne[ct] = jvalid[ct] ? ends[jn[ct]]   : -1;
        }
#pragma unroll
        for (int rt = 0; rt < 4; ++rt) {
            const int ibase = ilo + rt * 16 + q * 4;
#pragma unroll
            for (int reg = 0; reg < 4; ++reg) {
                const int i = ibase + reg;
                const bool rowValid = (i < M);
                const int ns = rowValid ? starts[i] : 0;
                const int ne = rowValid ? ends[i]   : -1;
                const float iinv = inv_norm[i];
                const float isq  = sq[i];
                float posp = 0.f, negp = 0.f;
#pragma unroll
                for (int ct = 0; ct < 4; ++ct) {
                    const float dot = acc[rt][ct][reg];
                    const int j = jn[ct];
                    float cosv = dot * iinv * jinv[ct];
                    cosv = fminf(fmaxf(cosv, -1.f), 1.f);
                    float tn = fmaxf(fabsf(cosv) - M_NEG, 0.f);
                    const float nterm = tn * tn;
                    const float d2 = fmaxf(isq + jsq[ct] - 2.f * dot, 0.f);
                    float tp = fmaxf(sqrtf(d2) - M_POS, 0.f);
                    const float pterm = tp * tp;
                    const bool dg = (j == i);
                    if (rowValid) {
                        const bool in_r = (j >= ns) && (j <= ne);
                        if (in_r && !dg) posp += pterm;
                        if (!in_r || dg) negp += nterm;
                    }
                    if (!isDiag && jvalid[ct]) {
                        const bool in_c = (i >= jns[ct]) && (i <= jne[ct]);
                        if (in_c && !dg) posc[ct] += pterm;
                        if (!in_c || dg) negc[ct] += nterm;
                    }
                }
#pragma unroll
                for (int m = 1; m < 16; m <<= 1) {
                    posp += __shfl_xor(posp, m, 64);
                    negp += __shfl_xor(negp, m, 64);
                }
                if (rowValid && rl == 0) {
                    atomicAdd(&pos_acc[i], posp);
                    atomicAdd(&neg_acc[i], negp);
                }
            }
        }
        if (!isDiag) {
#pragma unroll
            for (int ct = 0; ct < 4; ++ct) {
                posc[ct] += __shfl_xor(posc[ct], 16, 64);
                posc[ct] += __shfl_xor(posc[ct], 32, 64);
                negc[ct] += __shfl_xor(negc[ct], 16, 64);
                negc[ct] += __shfl_xor(negc[ct], 32, 64);
            }
            if (q == 0) {
#pragma unroll
                for (int ct = 0; ct < 4; ++ct) {
                    if (jvalid[ct]) {
                        atomicAdd(&pos_acc[jn[ct]], posc[ct]);
                        atomicAdd(&neg_acc[jn[ct]], negc[ct]);
                    }
                }
            }
        }
    } else {
        // fast path: every element is a negative for both its row and its column
#pragma unroll
        for (int rt = 0; rt < 4; ++rt) {
            const int ibase = ilo + rt * 16 + q * 4;
#pragma unroll
            for (int reg = 0; reg < 4; ++reg) {
                const int i = ibase + reg;
                const float iinv = inv_norm[i];
                float negp = 0.f;
#pragma unroll
                for (int ct = 0; ct < 4; ++ct) {
                    const float dot = acc[rt][ct][reg];
                    float cosv = dot * iinv * jinv[ct];
                    cosv = fminf(fmaxf(cosv, -1.f), 1.f);
                    float tn = fmaxf(fabsf(cosv) - M_NEG, 0.f);
                    const float nterm = tn * tn;
                    negp += nterm;
                    negc[ct] += nterm;
                }
#pragma unroll
                for (int m = 1; m < 16; m <<= 1)
                    negp += __shfl_xor(negp, m, 64);
                if ((i < M) && rl == 0)
                    atomicAdd(&neg_acc[i], negp);
            }
        }
        if (!isDiag) {
#pragma unroll
            for (int ct = 0; ct < 4; ++ct) {
                negc[ct] += __shfl_xor(negc[ct], 16, 64);
                negc[ct] += __shfl_xor(negc[ct], 32, 64);
            }
            if (q == 0) {
#pragma unroll
                for (int ct = 0; ct < 4; ++ct)
                    if (jvalid[ct])
                        atomicAdd(&neg_acc[jn[ct]], negc[ct]);
            }
        }
    }

    // ---- last-block finalize (fence/atomic by tid0 only — validated R7) ----
    __shared__ bool amLast;
    __syncthreads();
    if (tid == 0) {
        __threadfence();
        unsigned old = atomicAdd(counter, 1u);
        amLast = (old == (unsigned)(gridDim.x - 1));
    }
    __syncthreads();
    if (amLast) {
        __threadfence();
        float total = 0.f;
        int cnt = 0;
        for (int i = tid; i < M; i += 256) {
            const float pa = __hip_atomic_load(&pos_acc[i], __ATOMIC_RELAXED, __HIP_MEMORY_SCOPE_AGENT);
            const float na = __hip_atomic_load(&neg_acc[i], __ATOMIC_RELAXED, __HIP_MEMORY_SCOPE_AGENT);
            const int ns = starts[i], ne = ends[i];
            const int lo = max(ns, 0), hi = min(ne, N - 1);
            const int inr = max(hi - lo + 1, 0);
            const bool dg = (i >= ns) && (i <= ne);
            const int pos_cnt = inr - (dg ? 1 : 0);
            const int neg_cnt = N - inr + (dg ? 1 : 0);
            if (pos_cnt > 0 && neg_cnt > 0) {
                total += pa / (float)max(pos_cnt, 1)
                       + LAM_NEG * na / (float)max(neg_cnt, 1);
                cnt++;
            }
        }
        for (int o = 32; o > 0; o >>= 1) {
            total += __shfl_down(total, o, 64);
            cnt   += __shfl_down(cnt, o, 64);
        }
        __shared__ float fin_ts[4];
        __shared__ int   fin_cs[4];
        if ((tid & 63) == 0) { fin_ts[tid >> 6] = total; fin_cs[tid >> 6] = cnt; }
        __syncthreads();
        if (tid == 0) {
            float T = fin_ts[0] + fin_ts[1] + fin_ts[2] + fin_ts[3];
            int   C = fin_cs[0] + fin_cs[1] + fin_cs[2] + fin_cs[3];
            out[0] = (C > 0) ? T / (float)C : 0.f;
        }
    }
}

extern "C" void kernel_launch(void* const* d_in, const int* in_sizes, int n_in,
                              void* d_out, int out_size, void* d_ws, size_t ws_size,
                              hipStream_t stream) {
    const float* cb     = (const float*)d_in[0];
    const int*   starts = (const int*)d_in[1];
    const int*   ends   = (const int*)d_in[2];
    const int*   max_ip = (const int*)d_in[3];
    float* out = (float*)d_out;

    const int N = in_sizes[1];
    const int d = in_sizes[0] / N;

    char* ws = (char*)d_ws;
    unsigned char* cb_q = (unsigned char*)ws;
    size_t off = ((size_t)N * d + 255) & ~(size_t)255;
    float* sq       = (float*)(ws + off); off += (size_t)N * 4;
    float* inv_norm = (float*)(ws + off); off += (size_t)N * 4;
    float* pos_acc  = (float*)(ws + off); off += (size_t)N * 4;
    float* neg_acc  = (float*)(ws + off); off += (size_t)N * 4;
    unsigned* counter = (unsigned*)(ws + off); off += 256;

    // prep zeroes pos_acc/neg_acc/counter (2N+1 u32, contiguous)
    prep_kernel<<<N, 256, 0, stream>>>(cb, cb_q, sq, inv_norm,
                                       (unsigned*)pos_acc, 2 * N + 1, N, d);

    const int nb = N / 128;
    const int nBlocks = nb * (nb + 1) / 2;   // upper-triangular tiles
    gram_loss_kernel<<<nBlocks, 256, 0, stream>>>(cb_q, sq, inv_norm, starts, ends,
                                                  max_ip, pos_acc, neg_acc, counter,
                                                  out, N, d);
}

// Round 13
// 198.636 us; speedup vs baseline: 1.2012x; 1.0376x over previous
//
#include <hip/hip_runtime.h>
#include <hip/hip_bf16.h>
#include <stdint.h>

#define M_POS 0.5f
#define M_NEG 0.1f
#define LAM_NEG 1.0f

typedef __attribute__((ext_vector_type(4))) float floatx4;  // 16x16 MFMA accumulator
typedef __attribute__((ext_vector_type(8))) int   intx8;    // 32B fp8 operand (K=128)

union Frag8 { intx8 v; int4 q[2]; };

// ---------------- Kernel A: row sumsq, inv_norm, fp32 -> fp8(e4m3) quantize, zero accs ----
__global__ __launch_bounds__(256) void prep_kernel(
    const float* __restrict__ cb, unsigned char* __restrict__ cb_q,
    float* __restrict__ sq, float* __restrict__ inv_norm,
    unsigned* __restrict__ zero_base, int zero_len,
    int N, int d)
{
    const int gi = blockIdx.x * 256 + threadIdx.x;
    if (gi < zero_len) zero_base[gi] = 0u;

    const int row = blockIdx.x;
    const float* src = cb + (size_t)row * d;
    unsigned char* dst = cb_q + (size_t)row * d;
    const int t = threadIdx.x;

    float s = 0.f;
    for (int c = t * 4; c < d; c += 1024) {
        float4 v = *(const float4*)(src + c);
        s += v.x * v.x + v.y * v.y + v.z * v.z + v.w * v.w;
        int pk = __builtin_amdgcn_cvt_pk_fp8_f32(v.x, v.y, 0, false);   // bytes 0,1
        pk     = __builtin_amdgcn_cvt_pk_fp8_f32(v.z, v.w, pk, true);   // bytes 2,3
        *(int*)(dst + c) = pk;
    }
    for (int o = 32; o > 0; o >>= 1) s += __shfl_down(s, o, 64);
    __shared__ float wsum[4];
    if ((t & 63) == 0) wsum[t >> 6] = s;
    __syncthreads();
    if (t == 0) {
        float tot = wsum[0] + wsum[1] + wsum[2] + wsum[3];
        sq[row] = tot;
        inv_norm[row] = rsqrtf(tot);
    }
}

// ---------------- Kernel B: fused symmetric MX-fp8 Gram GEMM + loss epilogue + finalize ----
// R13: combine the two verified wins — MX 16x16x128 rate (R8: gram 128.5) and 16 waves/CU
// (R12: +6% from 4 waves/SIMD). 512-thread blocks, 8 waves, each wave computes 32x64
// (2x4 tiles): acc 32 AGPR + af[2] 16 + bf[4] 32 + bookkeeping ~= 110 regs <= 128 cap
// from __launch_bounds__(512,4) -> 4 waves/SIMD with MX. Same 128x128 block tile,
// 32 KB LDS, BK=128, xor swizzle, unit E8M0 scales (bit-exact vs non-scaled fp8).
// Canaries: WRITE_SIZE ~10 KB (spills), VGPR_Count <= 96.
// DO NOT: 64KB dbuf (R9), per-thread fences (R3), (256,4)+MX 64-reg cap (R10 spills).
__global__ __launch_bounds__(512, 4) void gram_loss_kernel(
    const unsigned char* __restrict__ A,   // N x d fp8
    const float* __restrict__ sq, const float* __restrict__ inv_norm,
    const int* __restrict__ starts, const int* __restrict__ ends,
    const int* __restrict__ max_ip,
    float* __restrict__ pos_acc, float* __restrict__ neg_acc,
    unsigned* __restrict__ counter, float* __restrict__ out,
    int N, int d)
{
    const int M = min(N, max_ip[0] + 1);

    // triangular decode: blockIdx.x -> (by, bx), by <= bx
    const int t = blockIdx.x;
    int bx = (int)((sqrtf(8.f * (float)t + 1.f) - 1.f) * 0.5f);
    while ((bx + 1) * (bx + 2) / 2 <= t) bx++;
    while (bx * (bx + 1) / 2 > t) bx--;
    const int by = t - bx * (bx + 1) / 2;

    const int rowBase = by * 128;
    const int colBase = bx * 128;
    const bool isDiag = (by == bx);

    __shared__ alignas(16) unsigned char ldsA[128 * 128];
    __shared__ alignas(16) unsigned char ldsB[128 * 128];

    const int tid  = threadIdx.x;
    const int wave = tid >> 6;          // 0..7
    const int lane = tid & 63;
    const int wr = (wave >> 1) * 32;    // 0,32,64,96
    const int wc = (wave & 1) * 64;     // 0,64

    floatx4 acc[2][4];
#pragma unroll
    for (int a = 0; a < 2; ++a)
#pragma unroll
        for (int b = 0; b < 4; ++b) acc[a][b] = (floatx4){0.f, 0.f, 0.f, 0.f};

    // staging: 8 waves x 16 rows = 128 rows per matrix; per wave 2 issues of 8 rows.
    const int sRow = lane >> 3;                         // 0..7
    const int sChk = lane & 7;                          // 16B chunk 0..7
    const int srcOffC = ((sChk ^ sRow) * 16);
    const int kTiles = d / 128;                         // 8

    // fragment-read constants: lane holds k = (lane>>4)*32 .. +31 of its row
    const int rl = lane & 15;
    const int g  = lane >> 4;       // 0..3 (k-group)
    const int rx = rl & 7;
    const int c0 = (((2 * g)     ^ rx) * 16);
    const int c1 = (((2 * g + 1) ^ rx) * 16);

    for (int kt = 0; kt < kTiles; ++kt) {
        __syncthreads();
        const int k0 = kt * 128;
#pragma unroll
        for (int h = 0; h < 2; ++h) {
            const int r = wave * 16 + h * 8 + sRow;     // tile row 0..127
            const unsigned char* ga = A + (size_t)(rowBase + r) * d + k0 + srcOffC;
            const unsigned char* gb = A + (size_t)(colBase + r) * d + k0 + srcOffC;
            __builtin_amdgcn_global_load_lds(
                (const __attribute__((address_space(1))) void*)ga,
                (__attribute__((address_space(3))) void*)(ldsA + r * 128 + sChk * 16), 16, 0, 0);
            __builtin_amdgcn_global_load_lds(
                (const __attribute__((address_space(1))) void*)gb,
                (__attribute__((address_space(3))) void*)(ldsB + r * 128 + sChk * 16), 16, 0, 0);
        }
        __syncthreads();

        Frag8 af[2], bf[4];
#pragma unroll
        for (int t2 = 0; t2 < 2; ++t2) {
            const unsigned char* pa = ldsA + (wr + t2 * 16 + rl) * 128;
            af[t2].q[0] = *(const int4*)(pa + c0);
            af[t2].q[1] = *(const int4*)(pa + c1);
        }
#pragma unroll
        for (int t4 = 0; t4 < 4; ++t4) {
            const unsigned char* pb = ldsB + (wc + t4 * 16 + rl) * 128;
            bf[t4].q[0] = *(const int4*)(pb + c0);
            bf[t4].q[1] = *(const int4*)(pb + c1);
        }
#pragma unroll
        for (int rt = 0; rt < 2; ++rt)
#pragma unroll
            for (int ct = 0; ct < 4; ++ct)
                acc[rt][ct] = __builtin_amdgcn_mfma_scale_f32_16x16x128_f8f6f4(
                    af[rt].v, bf[ct].v, acc[rt][ct], 0, 0, 0, 127, 0, 127);
    }

    // ---- epilogue (16x16 C/D: col=lane&15, row=(lane>>4)*4+reg); wave covers 32 rows ----
    const int q  = g;
    const int jlo = colBase + wc;        // wave j-window [jlo, jlo+63]
    const int ilo = rowBase + wr;        // wave i-window [ilo, ilo+31]

    int   jn[4];
    float jinv[4];
    bool  jvalid[4];
#pragma unroll
    for (int ct = 0; ct < 4; ++ct) {
        const int j = jlo + ct * 16 + rl;
        jn[ct]  = j;
        jinv[ct] = inv_norm[j];
        jvalid[ct] = (j < M);
    }

    // wave-uniform positive-pair possibility check (32 rows, 64 cols)
    bool posLane = false;
    {
        const int ri = ilo + (lane & 31);
        if (ri < M) posLane |= (ends[ri] >= jlo) && (starts[ri] <= jlo + 63);
        if (!isDiag) {
            const int cj = jlo + lane;
            if (cj < M) posLane |= (ends[cj] >= ilo) && (starts[cj] <= ilo + 31);
        }
    }
    const bool fullPath = (__ballot(posLane) != 0ULL);

    float posc[4] = {0.f, 0.f, 0.f, 0.f};
    float negc[4] = {0.f, 0.f, 0.f, 0.f};

    if (fullPath) {
        int   jns[4], jne[4];
        float jsq[4];
#pragma unroll
        for (int ct = 0; ct < 4; ++ct) {
            jsq[ct] = sq[jn[ct]];
            jns[ct] = jvalid[ct] ? starts[jn[ct]] : 0;
            jne[ct] = jvalid[ct] ? ends[jn[ct]]   : -1;
        }
#pragma unroll
        for (int rt = 0; rt < 2; ++rt) {
            const int ibase = ilo + rt * 16 + q * 4;
#pragma unroll
            for (int reg = 0; reg < 4; ++reg) {
                const int i = ibase + reg;
                const bool rowValid = (i < M);
                const int ns = rowValid ? starts[i] : 0;
                const int ne = rowValid ? ends[i]   : -1;
                const float iinv = inv_norm[i];
                const float isq  = sq[i];
                float posp = 0.f, negp = 0.f;
#pragma unroll
                for (int ct = 0; ct < 4; ++ct) {
                    const float dot = acc[rt][ct][reg];
                    const int j = jn[ct];
                    float cosv = dot * iinv * jinv[ct];
                    cosv = fminf(fmaxf(cosv, -1.f), 1.f);
                    float tn = fmaxf(fabsf(cosv) - M_NEG, 0.f);
                    const float nterm = tn * tn;
                    const float d2 = fmaxf(isq + jsq[ct] - 2.f * dot, 0.f);
                    float tp = fmaxf(sqrtf(d2) - M_POS, 0.f);
                    const float pterm = tp * tp;
                    const bool dg = (j == i);
                    if (rowValid) {
                        const bool in_r = (j >= ns) && (j <= ne);
                        if (in_r && !dg) posp += pterm;
                        if (!in_r || dg) negp += nterm;
                    }
                    if (!isDiag && jvalid[ct]) {
                        const bool in_c = (i >= jns[ct]) && (i <= jne[ct]);
                        if (in_c && !dg) posc[ct] += pterm;
                        if (!in_c || dg) negc[ct] += nterm;
                    }
                }
#pragma unroll
                for (int m = 1; m < 16; m <<= 1) {
                    posp += __shfl_xor(posp, m, 64);
                    negp += __shfl_xor(negp, m, 64);
                }
                if (rowValid && rl == 0) {
                    atomicAdd(&pos_acc[i], posp);
                    atomicAdd(&neg_acc[i], negp);
                }
            }
        }
        if (!isDiag) {
#pragma unroll
            for (int ct = 0; ct < 4; ++ct) {
                posc[ct] += __shfl_xor(posc[ct], 16, 64);
                posc[ct] += __shfl_xor(posc[ct], 32, 64);
                negc[ct] += __shfl_xor(negc[ct], 16, 64);
                negc[ct] += __shfl_xor(negc[ct], 32, 64);
            }
            if (q == 0) {
#pragma unroll
                for (int ct = 0; ct < 4; ++ct) {
                    if (jvalid[ct]) {
                        atomicAdd(&pos_acc[jn[ct]], posc[ct]);
                        atomicAdd(&neg_acc[jn[ct]], negc[ct]);
                    }
                }
            }
        }
    } else {
        // fast path: every element is a negative for both its row and its column
#pragma unroll
        for (int rt = 0; rt < 2; ++rt) {
            const int ibase = ilo + rt * 16 + q * 4;
#pragma unroll
            for (int reg = 0; reg < 4; ++reg) {
                const int i = ibase + reg;
                const float iinv = inv_norm[i];
                float negp = 0.f;
#pragma unroll
                for (int ct = 0; ct < 4; ++ct) {
                    const float dot = acc[rt][ct][reg];
                    float cosv = dot * iinv * jinv[ct];
                    cosv = fminf(fmaxf(cosv, -1.f), 1.f);
                    float tn = fmaxf(fabsf(cosv) - M_NEG, 0.f);
                    const float nterm = tn * tn;
                    negp += nterm;
                    negc[ct] += nterm;
                }
#pragma unroll
                for (int m = 1; m < 16; m <<= 1)
                    negp += __shfl_xor(negp, m, 64);
                if ((i < M) && rl == 0)
                    atomicAdd(&neg_acc[i], negp);
            }
        }
        if (!isDiag) {
#pragma unroll
            for (int ct = 0; ct < 4; ++ct) {
                negc[ct] += __shfl_xor(negc[ct], 16, 64);
                negc[ct] += __shfl_xor(negc[ct], 32, 64);
            }
            if (q == 0) {
#pragma unroll
                for (int ct = 0; ct < 4; ++ct)
                    if (jvalid[ct])
                        atomicAdd(&neg_acc[jn[ct]], negc[ct]);
            }
        }
    }

    // ---- last-block finalize (fence/atomic by tid0 only — validated R7) ----
    __shared__ bool amLast;
    __syncthreads();
    if (tid == 0) {
        __threadfence();
        unsigned old = atomicAdd(counter, 1u);
        amLast = (old == (unsigned)(gridDim.x - 1));
    }
    __syncthreads();
    if (amLast) {
        __threadfence();
        float total = 0.f;
        int cnt = 0;
        for (int i = tid; i < M; i += 512) {
            const float pa = __hip_atomic_load(&pos_acc[i], __ATOMIC_RELAXED, __HIP_MEMORY_SCOPE_AGENT);
            const float na = __hip_atomic_load(&neg_acc[i], __ATOMIC_RELAXED, __HIP_MEMORY_SCOPE_AGENT);
            const int ns = starts[i], ne = ends[i];
            const int lo = max(ns, 0), hi = min(ne, N - 1);
            const int inr = max(hi - lo + 1, 0);
            const bool dg = (i >= ns) && (i <= ne);
            const int pos_cnt = inr - (dg ? 1 : 0);
            const int neg_cnt = N - inr + (dg ? 1 : 0);
            if (pos_cnt > 0 && neg_cnt > 0) {
                total += pa / (float)max(pos_cnt, 1)
                       + LAM_NEG * na / (float)max(neg_cnt, 1);
                cnt++;
            }
        }
        for (int o = 32; o > 0; o >>= 1) {
            total += __shfl_down(total, o, 64);
            cnt   += __shfl_down(cnt, o, 64);
        }
        __shared__ float fin_ts[8];
        __shared__ int   fin_cs[8];
        if ((tid & 63) == 0) { fin_ts[tid >> 6] = total; fin_cs[tid >> 6] = cnt; }
        __syncthreads();
        if (tid == 0) {
            float T = 0.f; int C = 0;
            for (int w = 0; w < 8; ++w) { T += fin_ts[w]; C += fin_cs[w]; }
            out[0] = (C > 0) ? T / (float)C : 0.f;
        }
    }
}

extern "C" void kernel_launch(void* const* d_in, const int* in_sizes, int n_in,
                              void* d_out, int out_size, void* d_ws, size_t ws_size,
                              hipStream_t stream) {
    const float* cb     = (const float*)d_in[0];
    const int*   starts = (const int*)d_in[1];
    const int*   ends   = (const int*)d_in[2];
    const int*   max_ip = (const int*)d_in[3];
    float* out = (float*)d_out;

    const int N = in_sizes[1];
    const int d = in_sizes[0] / N;

    char* ws = (char*)d_ws;
    unsigned char* cb_q = (unsigned char*)ws;
    size_t off = ((size_t)N * d + 255) & ~(size_t)255;
    float* sq       = (float*)(ws + off); off += (size_t)N * 4;
    float* inv_norm = (float*)(ws + off); off += (size_t)N * 4;
    float* pos_acc  = (float*)(ws + off); off += (size_t)N * 4;
    float* neg_acc  = (float*)(ws + off); off += (size_t)N * 4;
    unsigned* counter = (unsigned*)(ws + off); off += 256;

    // prep zeroes pos_acc/neg_acc/counter (2N+1 u32, contiguous)
    prep_kernel<<<N, 256, 0, stream>>>(cb, cb_q, sq, inv_norm,
                                       (unsigned*)pos_acc, 2 * N + 1, N, d);

    const int nb = N / 128;
    const int nBlocks = nb * (nb + 1) / 2;   // upper-triangular tiles
    gram_loss_kernel<<<nBlocks, 512, 0, stream>>>(cb_q, sq, inv_norm, starts, ends,
                                                  max_ip, pos_acc, neg_acc, counter,
                                                  out, N, d);
}